// Round 12
// baseline (1243.116 us; speedup 1.0000x reference)
//
#include <hip/hip_runtime.h>

#define NT 64
#define GPB 32
#define NB 262144

struct P {
  const float* node_feat; const float* edge_feat; const int* ei;
  const float* W_ne; const float* b_ne; const float* g_ne; const float* be_ne;
  const float* W_ee; const float* b_ee;
  const float* msg_W1; const float* msg_b1; const float* msg_W2; const float* msg_b2;
  const float* upd_W1; const float* upd_b1; const float* upd_g1; const float* upd_be1;
  const float* upd_W2; const float* upd_b2; const float* upd_g2; const float* upd_be2;
  const float* Wp; const float* bp; const float* gp; const float* bep;
  const float* mW1; const float* mb1; const float* mg1; const float* mbe1;
  const float* mW2; const float* mb2; const float* mg2; const float* mbe2;
  const float* mW3; const float* mb3; const float* mg3; const float* mbe3;
  const float* mW4; const float* mb4;
  float* out;
};

// 1/sqrt(1+1e-5)
#define INVC 0.9999950000374997f

__device__ __forceinline__ float sigm(float x) {
  return __builtin_amdgcn_rcpf(1.0f + __expf(-x));
}

// exchange within lane pairs (2p <-> 2p+1): quad_perm [1,0,3,2] = 0xB1 (R5-verified)
__device__ __forceinline__ float dpp_xor1(float v) {
  return __builtin_bit_cast(float, __builtin_amdgcn_update_dpp(
      0, __builtin_bit_cast(int, v), 0xB1, 0xF, 0xF, false));
}

__device__ __forceinline__ float4 ld4(const float* p_) { return *(const float4*)p_; }

__device__ __forceinline__ void fma8(float hv, const float4 w0, const float4 w1,
                                     float (&a)[8]) {
  a[0] = fmaf(hv, w0.x, a[0]); a[1] = fmaf(hv, w0.y, a[1]);
  a[2] = fmaf(hv, w0.z, a[2]); a[3] = fmaf(hv, w0.w, a[3]);
  a[4] = fmaf(hv, w1.x, a[4]); a[5] = fmaf(hv, w1.y, a[5]);
  a[6] = fmaf(hv, w1.z, a[6]); a[7] = fmaf(hv, w1.w, a[7]);
}

// acc[8] += W[k][d0..d0+7]^T · h[k], k=0..K-1. Wd points at W[0] + d0 (divergent
// -> vector loads). 2-row double-buffered chunks: wa/wb = 8 float4 = 32 VGPRs
// total staging (R12: was 4-row/64 VGPRs -> hit the 256 cap and spilled, which
// throttled occupancy to ~3.5 waves/CU. Spill-free > deeper per-wave pipeline.)
template <int K, int LD>
__device__ __forceinline__ void gemm8(const float* Wd, const float (&h)[K],
                                      float (&a)[8]) {
  constexpr int NC = K / 2;
  static_assert(K % 2 == 0, "K must be a multiple of 2");
  float4 wa[4], wb[4];
#pragma unroll
  for (int r = 0; r < 2; r++) {
    wa[2 * r]     = ld4(Wd + r * LD);
    wa[2 * r + 1] = ld4(Wd + r * LD + 4);
  }
#pragma unroll
  for (int c = 0; c < NC; c++) {
    if (c + 1 < NC) {
      float4 (&nxt)[4] = (c & 1) ? wa : wb;   // c is unroll-static
#pragma unroll
      for (int r = 0; r < 2; r++) {
        nxt[2 * r]     = ld4(Wd + ((c + 1) * 2 + r) * LD);
        nxt[2 * r + 1] = ld4(Wd + ((c + 1) * 2 + r) * LD + 4);
      }
    }
    const float4 (&cur)[4] = (c & 1) ? wb : wa;
#pragma unroll
    for (int r = 0; r < 2; r++) fma8(h[c * 2 + r], cur[2 * r], cur[2 * r + 1], a);
  }
}

__device__ __forceinline__ void bias8(const float* b, float (&a)[8]) {
  float4 b0 = ld4(b), b1 = ld4(b + 4);
  a[0] = b0.x; a[1] = b0.y; a[2] = b0.z; a[3] = b0.w;
  a[4] = b1.x; a[5] = b1.y; a[6] = b1.z; a[7] = b1.w;
}

__device__ __forceinline__ void bnsig8(const float* gam, const float* bet, float (&a)[8]) {
  float4 g0 = ld4(gam), g1 = ld4(gam + 4), b0 = ld4(bet), b1 = ld4(bet + 4);
  a[0] = sigm(fmaf(g0.x * INVC, a[0], b0.x));
  a[1] = sigm(fmaf(g0.y * INVC, a[1], b0.y));
  a[2] = sigm(fmaf(g0.z * INVC, a[2], b0.z));
  a[3] = sigm(fmaf(g0.w * INVC, a[3], b0.w));
  a[4] = sigm(fmaf(g1.x * INVC, a[4], b1.x));
  a[5] = sigm(fmaf(g1.y * INVC, a[5], b1.y));
  a[6] = sigm(fmaf(g1.z * INVC, a[6], b1.z));
  a[7] = sigm(fmaf(g1.w * INVC, a[7], b1.w));
}

// own 8 values + partner's 8 -> canonical 16-vector (dims 0..15)
__device__ __forceinline__ void pairfull(const float (&m)[8], int par, float (&o)[16]) {
#pragma unroll
  for (int j = 0; j < 8; j++) {
    const float sw = dpp_xor1(m[j]);
    o[j]     = par ? sw : m[j];
    o[8 + j] = par ? m[j] : sw;
  }
}

// 2 lanes per graph (lane pair 2p,2p+1), 32 graphs per 1-wave block.
// LDS xs[160][32] = 20480 B -> 8 blocks/CU (= 2 waves/SIMD if VGPR<=256, no spill).
//   rows  0..79  : x[n][d] = row n*16+d (col = graph)
//   rows 80..159 : agg during GNN; p1 / MLP ping-pong after.
// Pairs read same addr (broadcast) or rows 8 apart in the same bank (2-way, free).
// Zero barriers (single wave; DS pipe is in-order within a wave).
__global__ __launch_bounds__(NT, 1) void gnn_kernel(P pp) {
  const int t = threadIdx.x;
  const int col = t >> 1;
  const int par = t & 1;
  const int d0 = par * 8;
  const int g = blockIdx.x * GPB + col;

  __shared__ float xs[160][GPB];

  // ---- raw edge features -> registers (statically indexed; selected per edge via cndmask)
  float ef[16];
  {
    const float4* q = (const float4*)(pp.edge_feat + (size_t)g * 16);
    float4 v0 = q[0], v1 = q[1], v2 = q[2], v3 = q[3];
    ef[0] = v0.x; ef[1] = v0.y; ef[2] = v0.z; ef[3] = v0.w;
    ef[4] = v1.x; ef[5] = v1.y; ef[6] = v1.z; ef[7] = v1.w;
    ef[8] = v2.x; ef[9] = v2.y; ef[10] = v2.z; ef[11] = v2.w;
    ef[12] = v3.x; ef[13] = v3.y; ef[14] = v3.z; ef[15] = v3.w;
  }

  // ---- node encoder: x[n][own 8 dims] -> LDS
#pragma unroll 1
  for (int n = 0; n < 5; n++) {
    float nfv[7];
#pragma unroll
    for (int k = 0; k < 7; k++) nfv[k] = pp.node_feat[(size_t)g * 35 + n * 7 + k];
    float a[8];
    bias8(pp.b_ne + d0, a);
#pragma unroll
    for (int k = 0; k < 7; k++) {
      const float* w = pp.W_ne + k * 16 + d0;
      fma8(nfv[k], ld4(w), ld4(w + 4), a);
    }
    const float gn = pp.g_ne[n] * INVC, bn = pp.be_ne[n];
#pragma unroll
    for (int j = 0; j < 8; j++) xs[n * 16 + d0 + j][col] = fmaf(gn, a[j], bn);
  }

  // ---- L message-passing layers
#pragma unroll 1
  for (int l = 0; l < 4; l++) {
    const float* mW1 = pp.msg_W1 + l * 576;
    const float* mb1 = pp.msg_b1 + l * 16;
    const float* mW2 = pp.msg_W2 + l * 256;
    const float* mb2 = pp.msg_b2 + l * 16;
    const float* uW1 = pp.upd_W1 + l * 512;
    const float* ub1 = pp.upd_b1 + l * 16;
    const float* uW2 = pp.upd_W2 + l * 256;
    const float* ub2 = pp.upd_b2 + l * 16;

    // zero my agg half
#pragma unroll
    for (int n = 0; n < 5; n++)
#pragma unroll
      for (int j = 0; j < 8; j++) xs[80 + n * 16 + d0 + j][col] = 0.f;

    // ---- phase A: per-edge messages
#pragma unroll 1
    for (int e = 0; e < 8; e++) {
      const int se = __builtin_amdgcn_readfirstlane(pp.ei[e]);
      const int de = __builtin_amdgcn_readfirstlane(pp.ei[8 + e]);

      // select this edge's raw features (static reg indices, uniform compares)
      float e0 = ef[0], e1 = ef[1];
#pragma unroll
      for (int q = 1; q < 8; q++) {
        e0 = (e == q) ? ef[2 * q] : e0;
        e1 = (e == q) ? ef[2 * q + 1] : e1;
      }

      float a[8];
      bias8(mb1 + d0, a);
      float hx[16];
#pragma unroll
      for (int k = 0; k < 16; k++) hx[k] = xs[de * 16 + k][col];
      gemm8<16, 16>(mW1 + d0, hx, a);
#pragma unroll
      for (int k = 0; k < 16; k++) hx[k] = xs[se * 16 + k][col];
      gemm8<16, 16>(mW1 + 256 + d0, hx, a);
      float ea4[4];
#pragma unroll
      for (int j = 0; j < 4; j++)
        ea4[j] = fmaf(e0, pp.W_ee[j], fmaf(e1, pp.W_ee[4 + j], pp.b_ee[j]));
      gemm8<4, 16>(mW1 + 512 + d0, ea4, a);

      float m1m[8];
#pragma unroll
      for (int j = 0; j < 8; j++) m1m[j] = sigm(a[j]);
      float m1all[16];
      pairfull(m1m, par, m1all);

      bias8(mb2 + d0, a);
      gemm8<16, 16>(mW2 + d0, m1all, a);
#pragma unroll
      for (int j = 0; j < 8; j++) xs[80 + de * 16 + d0 + j][col] += sigm(a[j]);
    }

    // ---- phase B: per-node update
#pragma unroll 1
    for (int n = 0; n < 5; n++) {
      int c = 0;
#pragma unroll
      for (int e = 0; e < 8; e++)
        c += (__builtin_amdgcn_readfirstlane(pp.ei[8 + e]) == n) ? 1 : 0;
      const float dr = 1.0f / (float)(c > 1 ? c : 1);

      float hx[16];
#pragma unroll
      for (int k = 0; k < 16; k++) hx[k] = xs[n * 16 + k][col];
      float xm[8];
#pragma unroll
      for (int j = 0; j < 8; j++) xm[j] = par ? hx[8 + j] : hx[j];

      float a[8];
      bias8(ub1 + d0, a);
      gemm8<16, 16>(uW1 + d0, hx, a);
#pragma unroll
      for (int k = 0; k < 16; k++) hx[k] = xs[80 + n * 16 + k][col] * dr;
      gemm8<16, 16>(uW1 + 256 + d0, hx, a);

      const float G1 = pp.upd_g1[l * 5 + n] * INVC, B1 = pp.upd_be1[l * 5 + n];
      float u1m[8];
#pragma unroll
      for (int j = 0; j < 8; j++) u1m[j] = sigm(fmaf(G1, a[j], B1));
      float u1all[16];
      pairfull(u1m, par, u1all);

      bias8(ub2 + d0, a);
      gemm8<16, 16>(uW2 + d0, u1all, a);
      const float G2 = pp.upd_g2[l * 5 + n] * INVC, B2 = pp.upd_be2[l * 5 + n];
#pragma unroll
      for (int j = 0; j < 8; j++)
        xs[n * 16 + d0 + j][col] = xm[j] + sigm(fmaf(G2, a[j], B2));
    }
  }

  // ---- pooling -> rows 80..95
  {
    float a[8];
    bias8(pp.bp + d0, a);
#pragma unroll 1
    for (int nb = 0; nb < 5; nb++) {
      float hx[16];
#pragma unroll
      for (int k = 0; k < 16; k++) hx[k] = xs[nb * 16 + k][col];
      gemm8<16, 16>(pp.Wp + nb * 256 + d0, hx, a);
    }
    bnsig8(pp.gp + d0, pp.bep + d0, a);
#pragma unroll
    for (int j = 0; j < 8; j++) xs[80 + d0 + j][col] = a[j];
  }

  // ---- MLP head (lane owns 32 of 64 outputs: grp*16 + d0 + j)
  // mlp1: rows 80..95 -> rows 0..63
  {
    float hx[16];
#pragma unroll
    for (int k = 0; k < 16; k++) hx[k] = xs[80 + k][col];
#pragma unroll 1
    for (int grp = 0; grp < 4; grp++) {
      const int ob = grp * 16 + d0;
      float a[8];
      bias8(pp.mb1 + ob, a);
      gemm8<16, 64>(pp.mW1 + ob, hx, a);
      bnsig8(pp.mg1 + ob, pp.mbe1 + ob, a);
#pragma unroll
      for (int j = 0; j < 8; j++) xs[ob + j][col] = a[j];
    }
  }
  // mlp2: rows 0..63 -> rows 80..143
  {
    float acc[4][8];
#pragma unroll
    for (int grp = 0; grp < 4; grp++) bias8(pp.mb2 + grp * 16 + d0, acc[grp]);
#pragma unroll 1
    for (int kb = 0; kb < 4; kb++) {
      float hx[16];
#pragma unroll
      for (int k = 0; k < 16; k++) hx[k] = xs[kb * 16 + k][col];
#pragma unroll
      for (int grp = 0; grp < 4; grp++)
        gemm8<16, 64>(pp.mW2 + (kb * 16) * 64 + grp * 16 + d0, hx, acc[grp]);
    }
#pragma unroll
    for (int grp = 0; grp < 4; grp++) {
      const int ob = grp * 16 + d0;
      bnsig8(pp.mg2 + ob, pp.mbe2 + ob, acc[grp]);
#pragma unroll
      for (int j = 0; j < 8; j++) xs[80 + ob + j][col] = acc[grp][j];
    }
  }
  // mlp3: rows 80..143 -> rows 0..63
  {
    float acc[4][8];
#pragma unroll
    for (int grp = 0; grp < 4; grp++) bias8(pp.mb3 + grp * 16 + d0, acc[grp]);
#pragma unroll 1
    for (int kb = 0; kb < 4; kb++) {
      float hx[16];
#pragma unroll
      for (int k = 0; k < 16; k++) hx[k] = xs[80 + kb * 16 + k][col];
#pragma unroll
      for (int grp = 0; grp < 4; grp++)
        gemm8<16, 64>(pp.mW3 + (kb * 16) * 64 + grp * 16 + d0, hx, acc[grp]);
    }
#pragma unroll
    for (int grp = 0; grp < 4; grp++) {
      const int ob = grp * 16 + d0;
      bnsig8(pp.mg3 + ob, pp.mbe3 + ob, acc[grp]);
#pragma unroll
      for (int j = 0; j < 8; j++) xs[ob + j][col] = acc[grp][j];
    }
  }
  // mlp4: rows 0..63 -> out (pair-split dot + DPP combine)
  {
    const float* w4 = pp.mW4 + par * 32;
    float4 wv[8];
#pragma unroll
    for (int r = 0; r < 8; r++) wv[r] = ld4(w4 + r * 4);
    float s0 = 0.f, s1 = 0.f, s2 = 0.f, s3 = 0.f;
#pragma unroll
    for (int r = 0; r < 8; r++) {
      s0 = fmaf(xs[par * 32 + r * 4 + 0][col], wv[r].x, s0);
      s1 = fmaf(xs[par * 32 + r * 4 + 1][col], wv[r].y, s1);
      s2 = fmaf(xs[par * 32 + r * 4 + 2][col], wv[r].z, s2);
      s3 = fmaf(xs[par * 32 + r * 4 + 3][col], wv[r].w, s3);
    }
    float s = (s0 + s1) + (s2 + s3);
    s += dpp_xor1(s);
    s += pp.mb4[0];
    if (par == 0) pp.out[g] = s;
  }
}

extern "C" void kernel_launch(void* const* d_in, const int* in_sizes, int n_in,
                              void* d_out, int out_size, void* d_ws, size_t ws_size,
                              hipStream_t stream) {
  P p;
  p.node_feat = (const float*)d_in[0];
  p.edge_feat = (const float*)d_in[1];
  p.ei        = (const int*)d_in[2];
  p.W_ne  = (const float*)d_in[3];  p.b_ne  = (const float*)d_in[4];
  p.g_ne  = (const float*)d_in[5];  p.be_ne = (const float*)d_in[6];
  p.W_ee  = (const float*)d_in[7];  p.b_ee  = (const float*)d_in[8];
  p.msg_W1 = (const float*)d_in[9];  p.msg_b1 = (const float*)d_in[10];
  p.msg_W2 = (const float*)d_in[11]; p.msg_b2 = (const float*)d_in[12];
  p.upd_W1 = (const float*)d_in[13]; p.upd_b1 = (const float*)d_in[14];
  p.upd_g1 = (const float*)d_in[15]; p.upd_be1 = (const float*)d_in[16];
  p.upd_W2 = (const float*)d_in[17]; p.upd_b2 = (const float*)d_in[18];
  p.upd_g2 = (const float*)d_in[19]; p.upd_be2 = (const float*)d_in[20];
  p.Wp  = (const float*)d_in[21]; p.bp  = (const float*)d_in[22];
  p.gp  = (const float*)d_in[23]; p.bep = (const float*)d_in[24];
  p.mW1 = (const float*)d_in[25]; p.mb1 = (const float*)d_in[26];
  p.mg1 = (const float*)d_in[27]; p.mbe1 = (const float*)d_in[28];
  p.mW2 = (const float*)d_in[29]; p.mb2 = (const float*)d_in[30];
  p.mg2 = (const float*)d_in[31]; p.mbe2 = (const float*)d_in[32];
  p.mW3 = (const float*)d_in[33]; p.mb3 = (const float*)d_in[34];
  p.mg3 = (const float*)d_in[35]; p.mbe3 = (const float*)d_in[36];
  p.mW4 = (const float*)d_in[37]; p.mb4 = (const float*)d_in[38];
  p.out = (float*)d_out;

  hipLaunchKernelGGL(gnn_kernel, dim3(NB / GPB), dim3(NT), 0, stream, p);
}

// Round 13
// 1217.217 us; speedup vs baseline: 1.0213x; 1.0213x over previous
//
#include <hip/hip_runtime.h>

#define NT 64
#define GPB 32
#define NB 262144

struct P {
  const float* node_feat; const float* edge_feat; const int* ei;
  const float* W_ne; const float* b_ne; const float* g_ne; const float* be_ne;
  const float* W_ee; const float* b_ee;
  const float* msg_W1; const float* msg_b1; const float* msg_W2; const float* msg_b2;
  const float* upd_W1; const float* upd_b1; const float* upd_g1; const float* upd_be1;
  const float* upd_W2; const float* upd_b2; const float* upd_g2; const float* upd_be2;
  const float* Wp; const float* bp; const float* gp; const float* bep;
  const float* mW1; const float* mb1; const float* mg1; const float* mbe1;
  const float* mW2; const float* mb2; const float* mg2; const float* mbe2;
  const float* mW3; const float* mb3; const float* mg3; const float* mbe3;
  const float* mW4; const float* mb4;
  float* out;
};

// 1/sqrt(1+1e-5)
#define INVC 0.9999950000374997f

__device__ __forceinline__ float sigm(float x) {
  return __builtin_amdgcn_rcpf(1.0f + __expf(-x));
}

// exchange within lane pairs (2p <-> 2p+1): quad_perm [1,0,3,2] = 0xB1 (R5-verified)
__device__ __forceinline__ float dpp_xor1(float v) {
  return __builtin_bit_cast(float, __builtin_amdgcn_update_dpp(
      0, __builtin_bit_cast(int, v), 0xB1, 0xF, 0xF, false));
}

__device__ __forceinline__ float4 ld4(const float* p_) { return *(const float4*)p_; }

__device__ __forceinline__ void fma8(float hv, const float4 w0, const float4 w1,
                                     float (&a)[8]) {
  a[0] = fmaf(hv, w0.x, a[0]); a[1] = fmaf(hv, w0.y, a[1]);
  a[2] = fmaf(hv, w0.z, a[2]); a[3] = fmaf(hv, w0.w, a[3]);
  a[4] = fmaf(hv, w1.x, a[4]); a[5] = fmaf(hv, w1.y, a[5]);
  a[6] = fmaf(hv, w1.z, a[6]); a[7] = fmaf(hv, w1.w, a[7]);
}

// Register-h variant (h already in VGPRs): acc[8] += W[k][d0..d0+7]^T · h[k].
template <int K, int LD>
__device__ __forceinline__ void gemm8(const float* Wd, const float (&h)[K],
                                      float (&a)[8]) {
  constexpr int NC = K / 2;
  static_assert(K % 2 == 0, "K must be even");
  float4 wa[4], wb[4];
#pragma unroll
  for (int r = 0; r < 2; r++) {
    wa[2 * r]     = ld4(Wd + r * LD);
    wa[2 * r + 1] = ld4(Wd + r * LD + 4);
  }
#pragma unroll
  for (int c = 0; c < NC; c++) {
    if (c + 1 < NC) {
      float4 (&nxt)[4] = (c & 1) ? wa : wb;
#pragma unroll
      for (int r = 0; r < 2; r++) {
        nxt[2 * r]     = ld4(Wd + ((c + 1) * 2 + r) * LD);
        nxt[2 * r + 1] = ld4(Wd + ((c + 1) * 2 + r) * LD + 4);
      }
    }
    const float4 (&cur)[4] = (c & 1) ? wb : wa;
#pragma unroll
    for (int r = 0; r < 2; r++) fma8(h[c * 2 + r], cur[2 * r], cur[2 * r + 1], a);
  }
}

// Streaming-h variant (R13): h[k] = hp[k*GPB]*scale read from LDS inside the
// loop -> only 2 h values live (vs a 16-reg hx buffer). Kills the VGPR spill
// that throttled residency in R11/R12.
template <int K, int LD>
__device__ __forceinline__ void gemm8s(const float* hp, float scale,
                                       const float* Wd, float (&a)[8]) {
  constexpr int NC = K / 2;
  static_assert(K % 2 == 0, "K must be even");
  float4 wa[4], wb[4];
  float h0 = hp[0] * scale, h1 = hp[GPB] * scale;
#pragma unroll
  for (int r = 0; r < 2; r++) {
    wa[2 * r]     = ld4(Wd + r * LD);
    wa[2 * r + 1] = ld4(Wd + r * LD + 4);
  }
#pragma unroll
  for (int c = 0; c < NC; c++) {
    const float hc0 = h0, hc1 = h1;
    if (c + 1 < NC) {
      h0 = hp[(2 * c + 2) * GPB] * scale;
      h1 = hp[(2 * c + 3) * GPB] * scale;
      float4 (&nxt)[4] = (c & 1) ? wa : wb;
#pragma unroll
      for (int r = 0; r < 2; r++) {
        nxt[2 * r]     = ld4(Wd + ((c + 1) * 2 + r) * LD);
        nxt[2 * r + 1] = ld4(Wd + ((c + 1) * 2 + r) * LD + 4);
      }
    }
    const float4 (&cur)[4] = (c & 1) ? wb : wa;
    fma8(hc0, cur[0], cur[1], a);
    fma8(hc1, cur[2], cur[3], a);
  }
}

__device__ __forceinline__ void bias8(const float* b, float (&a)[8]) {
  float4 b0 = ld4(b), b1 = ld4(b + 4);
  a[0] = b0.x; a[1] = b0.y; a[2] = b0.z; a[3] = b0.w;
  a[4] = b1.x; a[5] = b1.y; a[6] = b1.z; a[7] = b1.w;
}

__device__ __forceinline__ void bnsig8(const float* gam, const float* bet, float (&a)[8]) {
  float4 g0 = ld4(gam), g1 = ld4(gam + 4), b0 = ld4(bet), b1 = ld4(bet + 4);
  a[0] = sigm(fmaf(g0.x * INVC, a[0], b0.x));
  a[1] = sigm(fmaf(g0.y * INVC, a[1], b0.y));
  a[2] = sigm(fmaf(g0.z * INVC, a[2], b0.z));
  a[3] = sigm(fmaf(g0.w * INVC, a[3], b0.w));
  a[4] = sigm(fmaf(g1.x * INVC, a[4], b1.x));
  a[5] = sigm(fmaf(g1.y * INVC, a[5], b1.y));
  a[6] = sigm(fmaf(g1.z * INVC, a[6], b1.z));
  a[7] = sigm(fmaf(g1.w * INVC, a[7], b1.w));
}

// own 8 values + partner's 8 -> canonical 16-vector (dims 0..15)
__device__ __forceinline__ void pairfull(const float (&m)[8], int par, float (&o)[16]) {
#pragma unroll
  for (int j = 0; j < 8; j++) {
    const float sw = dpp_xor1(m[j]);
    o[j]     = par ? sw : m[j];
    o[8 + j] = par ? m[j] : sw;
  }
}

// 2 lanes per graph (lane pair 2p,2p+1), 32 graphs per 1-wave block.
// LDS xs[176][32] = 22528 B -> 7 blocks/CU.
//   rows  0..79  : x[n][d] = row n*16+d (col = graph)
//   rows 80..159 : agg during GNN; p1 / MLP ping-pong after
//   rows 160..175: raw edge features (R13: moved out of registers)
// Pairs read same addr (broadcast) or rows 8 apart (2-way, free). Zero barriers.
__global__ __launch_bounds__(NT, 1) void gnn_kernel(P pp) {
  const int t = threadIdx.x;
  const int col = t >> 1;
  const int par = t & 1;
  const int d0 = par * 8;
  const int g = blockIdx.x * GPB + col;

  __shared__ float xs[176][GPB];

  // ---- raw edge features -> LDS rows 160..175 (own half: 8 values per lane)
  {
    const float4* q = (const float4*)(pp.edge_feat + (size_t)g * 16 + d0);
    float4 v0 = q[0], v1 = q[1];
    xs[160 + d0 + 0][col] = v0.x; xs[160 + d0 + 1][col] = v0.y;
    xs[160 + d0 + 2][col] = v0.z; xs[160 + d0 + 3][col] = v0.w;
    xs[160 + d0 + 4][col] = v1.x; xs[160 + d0 + 5][col] = v1.y;
    xs[160 + d0 + 6][col] = v1.z; xs[160 + d0 + 7][col] = v1.w;
  }

  // ---- node encoder: x[n][own 8 dims] -> LDS
#pragma unroll 1
  for (int n = 0; n < 5; n++) {
    float nfv[7];
#pragma unroll
    for (int k = 0; k < 7; k++) nfv[k] = pp.node_feat[(size_t)g * 35 + n * 7 + k];
    float a[8];
    bias8(pp.b_ne + d0, a);
#pragma unroll
    for (int k = 0; k < 7; k++) {
      const float* w = pp.W_ne + k * 16 + d0;
      fma8(nfv[k], ld4(w), ld4(w + 4), a);
    }
    const float gn = pp.g_ne[n] * INVC, bn = pp.be_ne[n];
#pragma unroll
    for (int j = 0; j < 8; j++) xs[n * 16 + d0 + j][col] = fmaf(gn, a[j], bn);
  }

  // ---- L message-passing layers
#pragma unroll 1
  for (int l = 0; l < 4; l++) {
    const float* mW1 = pp.msg_W1 + l * 576;
    const float* mb1 = pp.msg_b1 + l * 16;
    const float* mW2 = pp.msg_W2 + l * 256;
    const float* mb2 = pp.msg_b2 + l * 16;
    const float* uW1 = pp.upd_W1 + l * 512;
    const float* ub1 = pp.upd_b1 + l * 16;
    const float* uW2 = pp.upd_W2 + l * 256;
    const float* ub2 = pp.upd_b2 + l * 16;

    // zero my agg half
#pragma unroll
    for (int n = 0; n < 5; n++)
#pragma unroll
      for (int j = 0; j < 8; j++) xs[80 + n * 16 + d0 + j][col] = 0.f;

    // ---- phase A: per-edge messages
#pragma unroll 1
    for (int e = 0; e < 8; e++) {
      const int se = __builtin_amdgcn_readfirstlane(pp.ei[e]);
      const int de = __builtin_amdgcn_readfirstlane(pp.ei[8 + e]);

      const float e0 = xs[160 + 2 * e][col];
      const float e1 = xs[161 + 2 * e][col];

      float a[8];
      bias8(mb1 + d0, a);
      gemm8s<16, 16>(&xs[de * 16][col], 1.0f, mW1 + d0, a);
      gemm8s<16, 16>(&xs[se * 16][col], 1.0f, mW1 + 256 + d0, a);
      float ea4[4];
#pragma unroll
      for (int j = 0; j < 4; j++)
        ea4[j] = fmaf(e0, pp.W_ee[j], fmaf(e1, pp.W_ee[4 + j], pp.b_ee[j]));
      gemm8<4, 16>(mW1 + 512 + d0, ea4, a);

      float m1m[8];
#pragma unroll
      for (int j = 0; j < 8; j++) m1m[j] = sigm(a[j]);
      float m1all[16];
      pairfull(m1m, par, m1all);

      bias8(mb2 + d0, a);
      gemm8<16, 16>(mW2 + d0, m1all, a);
#pragma unroll
      for (int j = 0; j < 8; j++) xs[80 + de * 16 + d0 + j][col] += sigm(a[j]);
    }

    // ---- phase B: per-node update
#pragma unroll 1
    for (int n = 0; n < 5; n++) {
      int c = 0;
#pragma unroll
      for (int e = 0; e < 8; e++)
        c += (__builtin_amdgcn_readfirstlane(pp.ei[8 + e]) == n) ? 1 : 0;
      const float dr = 1.0f / (float)(c > 1 ? c : 1);

      float xm[8];
#pragma unroll
      for (int j = 0; j < 8; j++) xm[j] = xs[n * 16 + d0 + j][col];

      float a[8];
      bias8(ub1 + d0, a);
      gemm8s<16, 16>(&xs[n * 16][col], 1.0f, uW1 + d0, a);
      gemm8s<16, 16>(&xs[80 + n * 16][col], dr, uW1 + 256 + d0, a);

      const float G1 = pp.upd_g1[l * 5 + n] * INVC, B1 = pp.upd_be1[l * 5 + n];
      float u1m[8];
#pragma unroll
      for (int j = 0; j < 8; j++) u1m[j] = sigm(fmaf(G1, a[j], B1));
      float u1all[16];
      pairfull(u1m, par, u1all);

      bias8(ub2 + d0, a);
      gemm8<16, 16>(uW2 + d0, u1all, a);
      const float G2 = pp.upd_g2[l * 5 + n] * INVC, B2 = pp.upd_be2[l * 5 + n];
#pragma unroll
      for (int j = 0; j < 8; j++)
        xs[n * 16 + d0 + j][col] = xm[j] + sigm(fmaf(G2, a[j], B2));
    }
  }

  // ---- pooling -> rows 80..95
  {
    float a[8];
    bias8(pp.bp + d0, a);
#pragma unroll 1
    for (int nb = 0; nb < 5; nb++)
      gemm8s<16, 16>(&xs[nb * 16][col], 1.0f, pp.Wp + nb * 256 + d0, a);
    bnsig8(pp.gp + d0, pp.bep + d0, a);
#pragma unroll
    for (int j = 0; j < 8; j++) xs[80 + d0 + j][col] = a[j];
  }

  // ---- MLP head (lane owns 32 of 64 outputs: grp*16 + d0 + j)
  // mlp1: rows 80..95 -> rows 0..63
#pragma unroll 1
  for (int grp = 0; grp < 4; grp++) {
    const int ob = grp * 16 + d0;
    float a[8];
    bias8(pp.mb1 + ob, a);
    gemm8s<16, 64>(&xs[80][col], 1.0f, pp.mW1 + ob, a);
    bnsig8(pp.mg1 + ob, pp.mbe1 + ob, a);
#pragma unroll
    for (int j = 0; j < 8; j++) xs[ob + j][col] = a[j];
  }
  // mlp2: rows 0..63 -> rows 80..143
  {
    float acc[4][8];
#pragma unroll
    for (int grp = 0; grp < 4; grp++) bias8(pp.mb2 + grp * 16 + d0, acc[grp]);
#pragma unroll 1
    for (int kb = 0; kb < 4; kb++) {
#pragma unroll
      for (int grp = 0; grp < 4; grp++)
        gemm8s<16, 64>(&xs[kb * 16][col], 1.0f,
                       pp.mW2 + (kb * 16) * 64 + grp * 16 + d0, acc[grp]);
    }
#pragma unroll
    for (int grp = 0; grp < 4; grp++) {
      const int ob = grp * 16 + d0;
      bnsig8(pp.mg2 + ob, pp.mbe2 + ob, acc[grp]);
#pragma unroll
      for (int j = 0; j < 8; j++) xs[80 + ob + j][col] = acc[grp][j];
    }
  }
  // mlp3: rows 80..143 -> rows 0..63
  {
    float acc[4][8];
#pragma unroll
    for (int grp = 0; grp < 4; grp++) bias8(pp.mb3 + grp * 16 + d0, acc[grp]);
#pragma unroll 1
    for (int kb = 0; kb < 4; kb++) {
#pragma unroll
      for (int grp = 0; grp < 4; grp++)
        gemm8s<16, 64>(&xs[80 + kb * 16][col], 1.0f,
                       pp.mW3 + (kb * 16) * 64 + grp * 16 + d0, acc[grp]);
    }
#pragma unroll
    for (int grp = 0; grp < 4; grp++) {
      const int ob = grp * 16 + d0;
      bnsig8(pp.mg3 + ob, pp.mbe3 + ob, acc[grp]);
#pragma unroll
      for (int j = 0; j < 8; j++) xs[ob + j][col] = acc[grp][j];
    }
  }
  // mlp4: rows 0..63 -> out (pair-split dot + DPP combine)
  {
    const float* w4 = pp.mW4 + par * 32;
    float s0 = 0.f, s1 = 0.f, s2 = 0.f, s3 = 0.f;
#pragma unroll
    for (int r = 0; r < 8; r++) {
      float4 wv = ld4(w4 + r * 4);
      s0 = fmaf(xs[par * 32 + r * 4 + 0][col], wv.x, s0);
      s1 = fmaf(xs[par * 32 + r * 4 + 1][col], wv.y, s1);
      s2 = fmaf(xs[par * 32 + r * 4 + 2][col], wv.z, s2);
      s3 = fmaf(xs[par * 32 + r * 4 + 3][col], wv.w, s3);
    }
    float s = (s0 + s1) + (s2 + s3);
    s += dpp_xor1(s);
    s += pp.mb4[0];
    if (par == 0) pp.out[g] = s;
  }
}

extern "C" void kernel_launch(void* const* d_in, const int* in_sizes, int n_in,
                              void* d_out, int out_size, void* d_ws, size_t ws_size,
                              hipStream_t stream) {
  P p;
  p.node_feat = (const float*)d_in[0];
  p.edge_feat = (const float*)d_in[1];
  p.ei        = (const int*)d_in[2];
  p.W_ne  = (const float*)d_in[3];  p.b_ne  = (const float*)d_in[4];
  p.g_ne  = (const float*)d_in[5];  p.be_ne = (const float*)d_in[6];
  p.W_ee  = (const float*)d_in[7];  p.b_ee  = (const float*)d_in[8];
  p.msg_W1 = (const float*)d_in[9];  p.msg_b1 = (const float*)d_in[10];
  p.msg_W2 = (const float*)d_in[11]; p.msg_b2 = (const float*)d_in[12];
  p.upd_W1 = (const float*)d_in[13]; p.upd_b1 = (const float*)d_in[14];
  p.upd_g1 = (const float*)d_in[15]; p.upd_be1 = (const float*)d_in[16];
  p.upd_W2 = (const float*)d_in[17]; p.upd_b2 = (const float*)d_in[18];
  p.upd_g2 = (const float*)d_in[19]; p.upd_be2 = (const float*)d_in[20];
  p.Wp  = (const float*)d_in[21]; p.bp  = (const float*)d_in[22];
  p.gp  = (const float*)d_in[23]; p.bep = (const float*)d_in[24];
  p.mW1 = (const float*)d_in[25]; p.mb1 = (const float*)d_in[26];
  p.mg1 = (const float*)d_in[27]; p.mbe1 = (const float*)d_in[28];
  p.mW2 = (const float*)d_in[29]; p.mb2 = (const float*)d_in[30];
  p.mg2 = (const float*)d_in[31]; p.mbe2 = (const float*)d_in[32];
  p.mW3 = (const float*)d_in[33]; p.mb3 = (const float*)d_in[34];
  p.mg3 = (const float*)d_in[35]; p.mbe3 = (const float*)d_in[36];
  p.mW4 = (const float*)d_in[37]; p.mb4 = (const float*)d_in[38];
  p.out = (float*)d_out;

  hipLaunchKernelGGL(gnn_kernel, dim3(NB / GPB), dim3(NT), 0, stream, p);
}